// Round 3
// baseline (386.397 us; speedup 1.0000x reference)
//
#include <hip/hip_runtime.h>
#include <hip/hip_bf16.h>

// Input: x [1, 512, 256, 256] f32, contiguous. Channel c = contiguous 65536 floats.
// Out: top-10 channel indices by mean (descending), int32.
// Single fused kernel: per-segment partial sums + last-block-finalize top-k.

#define C 512
#define HW 65536                 // 256*256
#define K_TOP 10
#define SEGS 8                   // segments per channel
#define SEG_FLOATS (HW / SEGS)   // 8192 floats per segment
#define NBLOCKS (C * SEGS)       // 4096

__global__ __launch_bounds__(256) void rank_channels_fused_kernel(
    const float* __restrict__ x, int* __restrict__ out,
    float* __restrict__ partials, unsigned int* __restrict__ counter) {
    const int b = blockIdx.x;              // 0..4095
    const int c = b >> 3;
    const int seg = b & 7;
    const float4* p = reinterpret_cast<const float4*>(
        x + (size_t)c * HW + (size_t)seg * SEG_FLOATS);
    const int tid = threadIdx.x;

    float s = 0.f;
#pragma unroll
    for (int i = 0; i < 8; ++i) {          // 8 * 256 threads * 4 floats = 8192
        float4 v = p[tid + i * 256];
        s += (v.x + v.y) + (v.z + v.w);
    }

    // wave-64 shuffle reduction (no barrier needed inside a wave)
#pragma unroll
    for (int off = 32; off > 0; off >>= 1) s += __shfl_down(s, off, 64);

    __shared__ float ps[4];
    if ((tid & 63) == 0) ps[tid >> 6] = s;
    __syncthreads();

    __shared__ int is_last;
    if (tid == 0) {
        partials[b] = (ps[0] + ps[1]) + (ps[2] + ps[3]);
        __threadfence();                           // release partials[b]
        unsigned int old = atomicAdd(counter, 1u); // device-scope
        is_last = (old == NBLOCKS - 1) ? 1 : 0;
    }
    __syncthreads();
    if (!is_last) return;

    // ---- last block finalizes: deterministic per-channel totals + top-k ----
    __threadfence();                               // acquire all partials
    __shared__ float vals[C];
#pragma unroll
    for (int r = 0; r < 2; ++r) {                  // 256 threads cover 512 channels
        int ch = tid + r * 256;
        float v = 0.f;
#pragma unroll
        for (int i = 0; i < SEGS; ++i) v += partials[ch * SEGS + i];
        vals[ch] = v;
    }
    __syncthreads();

    if (tid < 64) {
        // each lane owns 8 channels: lane + 64*j
        float lv[8];
        int   li[8];
#pragma unroll
        for (int j = 0; j < 8; ++j) {
            li[j] = tid + 64 * j;
            lv[j] = vals[li[j]];
        }
        for (int k = 0; k < K_TOP; ++k) {
            // local argmax over this lane's 8 (tie -> lower index)
            float bv = lv[0]; int bi = li[0];
#pragma unroll
            for (int j = 1; j < 8; ++j)
                if (lv[j] > bv || (lv[j] == bv && li[j] < bi)) { bv = lv[j]; bi = li[j]; }
            // 64-lane butterfly argmax — all lanes converge to the same winner
#pragma unroll
            for (int m = 1; m < 64; m <<= 1) {
                float ov = __shfl_xor(bv, m, 64);
                int   oi = __shfl_xor(bi, m, 64);
                if (ov > bv || (ov == bv && oi < bi)) { bv = ov; bi = oi; }
            }
            if (tid == 0) out[k] = bi;
            // remove winner from the owning lane
#pragma unroll
            for (int j = 0; j < 8; ++j)
                if (li[j] == bi) lv[j] = -__builtin_inff();
        }
    }
}

extern "C" void kernel_launch(void* const* d_in, const int* in_sizes, int n_in,
                              void* d_out, int out_size, void* d_ws, size_t ws_size,
                              hipStream_t stream) {
    const float* x = (const float*)d_in[0];
    int* out = (int*)d_out;
    // ws layout: [0..3] atomic counter, [64..] partials (4096 floats)
    unsigned int* counter = (unsigned int*)d_ws;
    float* partials = (float*)((char*)d_ws + 64);

    hipMemsetAsync(counter, 0, sizeof(unsigned int), stream);  // ws is poisoned 0xAA
    rank_channels_fused_kernel<<<NBLOCKS, 256, 0, stream>>>(x, out, partials, counter);
}

// Round 6
// 194.834 us; speedup vs baseline: 1.9832x; 1.9832x over previous
//
#include <hip/hip_runtime.h>
#include <hip/hip_bf16.h>

// Input: x [1, 512, 256, 256] f32, contiguous. Channel c = contiguous 65536 floats.
// Out: top-10 channel indices by mean (descending), int32.
//
// R3 lesson: fused single-kernel w/ one atomic counter serialized 4096
// device-scope same-address atomics (~61ns each = +225us). Two launches it is.

#define C 512
#define HW 65536                 // 256*256
#define K_TOP 10
#define SEGS 8                   // segments per channel
#define SEG_FLOATS (HW / SEGS)   // 8192 floats per segment
#define NBLOCKS (C * SEGS)       // 4096

// Grid: 4096 blocks x 256 threads. Each block sums one 8192-float contiguous
// segment (8 float4/thread), fully coalesced. 16 blocks/CU of work.
__global__ __launch_bounds__(256) void partial_sum_kernel(
    const float* __restrict__ x, float* __restrict__ partials) {
    const int b = blockIdx.x;              // 0..4095
    const int c = b >> 3;
    const int seg = b & 7;
    const float4* p = reinterpret_cast<const float4*>(
        x + (size_t)c * HW + (size_t)seg * SEG_FLOATS);
    const int tid = threadIdx.x;

    float s = 0.f;
#pragma unroll
    for (int i = 0; i < 8; ++i) {          // 8 * 256 threads * 4 floats = 8192
        float4 v = p[tid + i * 256];
        s += (v.x + v.y) + (v.z + v.w);
    }

    // wave-64 shuffle reduction (no barrier inside a wave)
#pragma unroll
    for (int off = 32; off > 0; off >>= 1) s += __shfl_down(s, off, 64);

    __shared__ float ps[4];
    if ((tid & 63) == 0) ps[tid >> 6] = s;
    __syncthreads();
    if (tid == 0) partials[b] = (ps[0] + ps[1]) + (ps[2] + ps[3]);
}

// Single wave, zero barriers, zero LDS. Each lane owns 8 channels
// (ch = lane + 64*j); a channel's 8 partials are contiguous -> two float4
// loads. 10 rounds of {local argmax over 8, 64-lane butterfly argmax}.
__global__ __launch_bounds__(64) void topk_kernel(
    const float* __restrict__ partials, int* __restrict__ out) {
    const int lane = threadIdx.x;

    float lv[8];
    int   li[8];
#pragma unroll
    for (int j = 0; j < 8; ++j) {
        const int ch = lane + 64 * j;
        li[j] = ch;
        const float4* p = reinterpret_cast<const float4*>(partials + ch * SEGS);
        float4 a = p[0], b = p[1];
        lv[j] = ((a.x + a.y) + (a.z + a.w)) + ((b.x + b.y) + (b.z + b.w));
    }

    for (int k = 0; k < K_TOP; ++k) {
        // local argmax over this lane's 8 (tie -> lower index)
        float bv = lv[0]; int bi = li[0];
#pragma unroll
        for (int j = 1; j < 8; ++j)
            if (lv[j] > bv || (lv[j] == bv && li[j] < bi)) { bv = lv[j]; bi = li[j]; }
        // 64-lane butterfly argmax — all lanes converge to the same winner
#pragma unroll
        for (int m = 1; m < 64; m <<= 1) {
            float ov = __shfl_xor(bv, m, 64);
            int   oi = __shfl_xor(bi, m, 64);
            if (ov > bv || (ov == bv && oi < bi)) { bv = ov; bi = oi; }
        }
        if (lane == 0) out[k] = bi;
        // owning lane removes the winner
#pragma unroll
        for (int j = 0; j < 8; ++j)
            if (li[j] == bi) lv[j] = -__builtin_inff();
    }
}

extern "C" void kernel_launch(void* const* d_in, const int* in_sizes, int n_in,
                              void* d_out, int out_size, void* d_ws, size_t ws_size,
                              hipStream_t stream) {
    const float* x = (const float*)d_in[0];
    int* out = (int*)d_out;
    float* partials = (float*)d_ws;        // 4096 floats of scratch

    partial_sum_kernel<<<NBLOCKS, 256, 0, stream>>>(x, partials);
    topk_kernel<<<1, 64, 0, stream>>>(partials, out);
}